// Round 3
// baseline (470.867 us; speedup 1.0000x reference)
//
#include <hip/hip_runtime.h>

// Problem constants
#define NN    8192          // N
#define DD    384           // dim
#define RR    64            // rank
#define BNROW 131072        // B*N
#define NGRP  2048          // B*g

typedef __attribute__((ext_vector_type(8))) short short8;            // 8 bf16 (A/B frag)
typedef __attribute__((ext_vector_type(4))) float floatx4;           // C/D frag
typedef __attribute__((ext_vector_type(4))) unsigned short ushortx4; // 4 bf16 (8B load)

__device__ __forceinline__ float silu_f(float x) {
    return x / (1.0f + __expf(-x));
}

// RNE round fp32 -> bf16 bits (low 16)
__device__ __forceinline__ unsigned bfr(float x) {
    unsigned u = __float_as_uint(x);
    return (u + 0x7fffu + ((u >> 16) & 1u)) >> 16;
}

// pack two fp32 -> two bf16 (RNE) in one uint
__device__ __forceinline__ unsigned bf2(float a, float b) {
    return bfr(a) | (bfr(b) << 16);
}

// bf16 bits -> fp32
__device__ __forceinline__ float b2f(unsigned short v) {
    return __uint_as_float(((unsigned)v) << 16);
}

union S8 { unsigned u[4]; short8 s; };
union S8H { unsigned short h[8]; short8 s; };

// ---------------------------------------------------------------------------
// Kernel P (prep): one-time bf16 conversion of the shared weights into the
// workspace (Wd 64x384, Wu 384x64, Wa 64x64; all L2-resident for the run).
// ---------------------------------------------------------------------------
__global__ __launch_bounds__(256) void kP(const float* __restrict__ Wd,
                                          const float* __restrict__ Wu,
                                          const float* __restrict__ Wa,
                                          unsigned short* __restrict__ WdB,
                                          unsigned short* __restrict__ WuB,
                                          unsigned short* __restrict__ WaB) {
    int i = blockIdx.x * 256 + threadIdx.x;
    const float* s;
    unsigned short* d;
    if (i < 6144)        { s = Wd + i * 4;           d = WdB + i * 4; }
    else if (i < 12288)  { s = Wu + (i - 6144) * 4;  d = WuB + (i - 6144) * 4; }
    else                 { s = Wa + (i - 12288) * 4; d = WaB + (i - 12288) * 4; }
    float4 v = *(const float4*)s;
    *(uint2*)d = make_uint2(bf2(v.x, v.y), bf2(v.z, v.w));
}

// ---------------------------------------------------------------------------
// Kernel A (MFMA): h = silu(input @ Wd^T + bd), h stored BF16.
// No LDS; B-frags straight from L2-resident WdB. Block = 64 rows, grid 2048.
// ---------------------------------------------------------------------------
__global__ __launch_bounds__(256) void kA(const float* __restrict__ in,
                                          const unsigned short* __restrict__ WdB,
                                          const float* __restrict__ bd,
                                          unsigned short* __restrict__ h) {
    const int tid = threadIdx.x;
    const int lane = tid & 63, w = tid >> 6;
    const int quad = lane >> 4, lr = lane & 15;
    const int grow = blockIdx.x * 64 + w * 16 + lr;    // this lane's A-row
    const float* arow = in + grow * DD + quad * 8;

    float4 v0[12], v1[12];
    #pragma unroll
    for (int ks = 0; ks < 12; ++ks) {
        v0[ks] = *(const float4*)(arow + ks * 32);
        v1[ks] = *(const float4*)(arow + ks * 32 + 4);
    }

    floatx4 acc[4] = {};
    #pragma unroll
    for (int ks = 0; ks < 12; ++ks) {
        S8 a;
        a.u[0] = bf2(v0[ks].x, v0[ks].y); a.u[1] = bf2(v0[ks].z, v0[ks].w);
        a.u[2] = bf2(v1[ks].x, v1[ks].y); a.u[3] = bf2(v1[ks].z, v1[ks].w);
        #pragma unroll
        for (int n = 0; n < 4; ++n) {
            const short8 b = *(const short8*)&WdB[(n * 16 + lr) * DD + ks * 32 + quad * 8];
            acc[n] = __builtin_amdgcn_mfma_f32_16x16x32_bf16(a.s, b, acc[n], 0, 0, 0);
        }
    }
    // D layout: row = quad*4 + i, col = n*16 + lr
    const int orow0 = blockIdx.x * 64 + w * 16 + quad * 4;
    #pragma unroll
    for (int n = 0; n < 4; ++n) {
        float bb = bd[n * 16 + lr];
        #pragma unroll
        for (int i = 0; i < 4; ++i)
            h[(orow0 + i) * 64 + n * 16 + lr] =
                (unsigned short)bfr(silu_f(acc[n][i] + bb));
    }
}

// ---------------------------------------------------------------------------
// Kernel B (MFMA, split-bf16): per (b,g) group, one block (4 waves):
//   X = gather(h, idx0); f = U^T X; f += silu(LN_r(f) @ Wa^T + ba); y1 = U f
// Buffers (stride 72, 36.9 KB, 4 blocks/CU):
//   AH: Ut_hi [s][t]  (INTACT all kernel -- m3 A-frags read its COLUMNS)
//   AL: Ut_lo [s][t]  (intact likewise)
//   BH: Xt (bf16) [r][t] -> fT_hi [r][s]
//   BL: LNf [s][r] (wave-private rows) -> fT_lo [r][s]
// vs R2: no U global re-read, no hi/lo re-split, no AH/AL restage. m3's
// A-operand U[p][s] = Ut[s][p] comes from AH/AL column reads (32 ds_read_u16,
// 4-way bank conflict across quads ~1.6x -- cheaper than the restage).
// Numerics bit-identical to R2.
// ---------------------------------------------------------------------------
__global__ __launch_bounds__(256) void kB(const unsigned short* __restrict__ h,
                                          const float* __restrict__ U1,
                                          const int*   __restrict__ idx0,
                                          const unsigned short* __restrict__ WaB,
                                          const float* __restrict__ ba,
                                          const float* __restrict__ gamma,
                                          const float* __restrict__ beta,
                                          unsigned short* __restrict__ y1) {
    __shared__ unsigned short AH[64 * 72];
    __shared__ unsigned short AL[64 * 72];
    __shared__ unsigned short BH[64 * 72];
    __shared__ unsigned short BL[64 * 72];
    const int tid = threadIdx.x;
    // XCD-chunked swizzle (2048 % 8 == 0 -> bijective)
    const int bg = ((blockIdx.x & 7) << 8) | (blockIdx.x >> 3);
    const int b  = bg >> 7;
    const float* U = U1 + bg * 4096;

    // ---- stage: Ut = U^T (hi/lo), Xt = X^T (bf16 pass-through), transposed
    #pragma unroll
    for (int it = 0; it < 4; ++it) {
        int idx = it * 256 + tid;
        int row = idx >> 4;          // t
        int kq  = idx & 15;          // col group
        float4 u = *(const float4*)(U + row * 64 + kq * 4);
        int src = idx0[bg * 64 + row];
        ushortx4 x = *(const ushortx4*)&h[(b * NN + src) * 64 + kq * 4];
        float uv[4] = {u.x, u.y, u.z, u.w};
        #pragma unroll
        for (int j = 0; j < 4; ++j) {
            unsigned uh = bfr(uv[j]);
            AH[(4 * kq + j) * 72 + row] = (unsigned short)uh;
            AL[(4 * kq + j) * 72 + row] = (unsigned short)bfr(uv[j] - __uint_as_float(uh << 16));
            BH[(4 * kq + j) * 72 + row] = x[j];
        }
    }
    __syncthreads();

    const int lane = tid & 63, w = tid >> 6;
    const int quad = lane >> 4, lr = lane & 15;
    const int mrow = w * 16 + lr;

    // ---- m1: f[s][r] = sum_t U[t][s] X[t][r]  (U split 2-product, X bf16)
    floatx4 f[4] = {};
    #pragma unroll
    for (int k = 0; k < 2; ++k) {
        const short8 aH = *(const short8*)&AH[mrow * 72 + k * 32 + quad * 8];
        const short8 aL = *(const short8*)&AL[mrow * 72 + k * 32 + quad * 8];
        #pragma unroll
        for (int n = 0; n < 4; ++n) {
            const short8 bh = *(const short8*)&BH[(n * 16 + lr) * 72 + k * 32 + quad * 8];
            f[n] = __builtin_amdgcn_mfma_f32_16x16x32_bf16(aH, bh, f[n], 0, 0, 0);
            f[n] = __builtin_amdgcn_mfma_f32_16x16x32_bf16(aL, bh, f[n], 0, 0, 0);
        }
    }

    // ---- LN over r. D layout: row s = 16w + quad*4 + i; masks 1..8 stay
    // inside the 16-lane group. LNf -> BL rows [16w,16w+16): wave-private.
    float gv[4], bv[4];
    #pragma unroll
    for (int n = 0; n < 4; ++n) { gv[n] = gamma[n * 16 + lr]; bv[n] = beta[n * 16 + lr]; }
    #pragma unroll
    for (int i = 0; i < 4; ++i) {
        float sm = f[0][i] + f[1][i] + f[2][i] + f[3][i];
        float sq = f[0][i]*f[0][i] + f[1][i]*f[1][i] + f[2][i]*f[2][i] + f[3][i]*f[3][i];
        #pragma unroll
        for (int mask = 1; mask <= 8; mask <<= 1) {
            sm += __shfl_xor(sm, mask, 64);
            sq += __shfl_xor(sq, mask, 64);
        }
        float mean = sm * 0.015625f;
        float var  = sq * 0.015625f - mean * mean;
        float rstd = rsqrtf(var + 1e-5f);
        int srow = w * 16 + quad * 4 + i;
        #pragma unroll
        for (int n = 0; n < 4; ++n) {
            float ln = (f[n][i] - mean) * rstd * gv[n] + bv[n];
            BL[srow * 72 + n * 16 + lr] = (unsigned short)bfr(ln);
        }
    }

    // ---- m2: a[s][j] = sum_r LNf[s][r] Wa[j][r]; A from BL (wave-private
    // rows), B straight from global (WaB is 8 KB, L1/L2-resident).
    floatx4 av[4] = {};
    #pragma unroll
    for (int k = 0; k < 2; ++k) {
        const short8 a2 = *(const short8*)&BL[mrow * 72 + k * 32 + quad * 8];
        #pragma unroll
        for (int n = 0; n < 4; ++n) {
            const short8 bw = *(const short8*)&WaB[(n * 16 + lr) * 64 + k * 32 + quad * 8];
            av[n] = __builtin_amdgcn_mfma_f32_16x16x32_bf16(a2, bw, av[n], 0, 0, 0);
        }
    }
    float bav[4];
    #pragma unroll
    for (int n = 0; n < 4; ++n) bav[n] = ba[n * 16 + lr];
    #pragma unroll
    for (int n = 0; n < 4; ++n)
        #pragma unroll
        for (int i = 0; i < 4; ++i)
            f[n][i] += silu_f(av[n][i] + bav[n]);

    __syncthreads();   // all waves done reading Xt (BH) in m1 and LNf (BL) in m2

    // ---- write fT (hi/lo) into BH/BL. AH/AL (Ut) remain intact.
    #pragma unroll
    for (int n = 0; n < 4; ++n)
        #pragma unroll
        for (int i = 0; i < 4; ++i) {
            float v = f[n][i];
            unsigned hb = bfr(v);
            BH[(n * 16 + lr) * 72 + w * 16 + quad * 4 + i] = (unsigned short)hb;
            BL[(n * 16 + lr) * 72 + w * 16 + quad * 4 + i] =
                (unsigned short)bfr(v - __uint_as_float(hb << 16));
        }
    __syncthreads();   // fT complete across waves

    // ---- m3: y[p][r] = sum_s U[p][s] f[s][r]  (split 3-product)
    // A-frags: U[p][s] = Ut[s][p] -> column reads of AH/AL (p = mrow).
    floatx4 y[4] = {};
    #pragma unroll
    for (int k = 0; k < 2; ++k) {
        S8H aH, aL;
        #pragma unroll
        for (int j = 0; j < 8; ++j) {
            int rr = k * 32 + quad * 8 + j;
            aH.h[j] = AH[rr * 72 + mrow];
            aL.h[j] = AL[rr * 72 + mrow];
        }
        #pragma unroll
        for (int n = 0; n < 4; ++n) {
            const short8 bh = *(const short8*)&BH[(n * 16 + lr) * 72 + k * 32 + quad * 8];
            const short8 bl = *(const short8*)&BL[(n * 16 + lr) * 72 + k * 32 + quad * 8];
            y[n] = __builtin_amdgcn_mfma_f32_16x16x32_bf16(aH.s, bh, y[n], 0, 0, 0);
            y[n] = __builtin_amdgcn_mfma_f32_16x16x32_bf16(aH.s, bl, y[n], 0, 0, 0);
            y[n] = __builtin_amdgcn_mfma_f32_16x16x32_bf16(aL.s, bh, y[n], 0, 0, 0);
        }
    }
    const int orow = bg * 64 + w * 16 + quad * 4;
    #pragma unroll
    for (int n = 0; n < 4; ++n)
        #pragma unroll
        for (int i = 0; i < 4; ++i)
            y1[(orow + i) * 64 + n * 16 + lr] = (unsigned short)bfr(y[n][i]);
}

// ---------------------------------------------------------------------------
// Kernel C (MFMA): out = (gather(y1, idx1) + y1 + h) @ Wu^T + bu
// y1/h arrive bf16 (8B loads); X summed in fp32 then SPLIT hi/lo bf16.
// LDS 18.4 KB -> 8 blocks/CU.
// ---------------------------------------------------------------------------
__global__ __launch_bounds__(256) void kC(const unsigned short* __restrict__ h,
                                          const unsigned short* __restrict__ y1,
                                          const int*   __restrict__ idx1,
                                          const unsigned short* __restrict__ WuB,
                                          const float* __restrict__ bu,
                                          float* __restrict__ out) {
    __shared__ unsigned short XsH[64 * 72];   // [m][k] hi, stride 72
    __shared__ unsigned short XsL[64 * 72];   // [m][k] lo
    const int tid = threadIdx.x;
    const int bid = ((blockIdx.x & 7) << 8) | (blockIdx.x >> 3);  // XCD swizzle
    const int m0 = bid * 64;
    const int b  = m0 >> 13;
    const int n0 = m0 & (NN - 1);

    // stage X = gather(y1) + y1 + h (fp32 sum), split into hi/lo bf16
    #pragma unroll
    for (int it = 0; it < 4; ++it) {
        int idx = it * 256 + tid;
        int r = idx >> 4, kq = idx & 15;
        int i1 = idx1[b * NN + n0 + r];
        const ushortx4 ya = *(const ushortx4*)&y1[(b * NN + i1) * 64 + kq * 4];
        const ushortx4 yb = *(const ushortx4*)&y1[(m0 + r) * 64 + kq * 4];
        const ushortx4 hh = *(const ushortx4*)&h [(m0 + r) * 64 + kq * 4];
        #pragma unroll
        for (int j = 0; j < 4; ++j) {
            float xv = b2f(ya[j]) + b2f(yb[j]) + b2f(hh[j]);
            unsigned xh = bfr(xv);
            XsH[r * 72 + kq * 4 + j] = (unsigned short)xh;
            XsL[r * 72 + kq * 4 + j] =
                (unsigned short)bfr(xv - __uint_as_float(xh << 16));
        }
    }
    __syncthreads();

    const int lane = tid & 63, w = tid >> 6;
    const int quad = lane >> 4, lr = lane & 15;
    const short8 a0h = *(const short8*)&XsH[(w * 16 + lr) * 72 + quad * 8];
    const short8 a0l = *(const short8*)&XsL[(w * 16 + lr) * 72 + quad * 8];
    const short8 a1h = *(const short8*)&XsH[(w * 16 + lr) * 72 + 32 + quad * 8];
    const short8 a1l = *(const short8*)&XsL[(w * 16 + lr) * 72 + 32 + quad * 8];
    const int orow0 = m0 + w * 16 + quad * 4;

    #pragma unroll
    for (int nt = 0; nt < 24; ++nt) {
        const short8 b0 = *(const short8*)&WuB[(nt * 16 + lr) * 64 + quad * 8];
        const short8 b1 = *(const short8*)&WuB[(nt * 16 + lr) * 64 + 32 + quad * 8];
        floatx4 d = {};
        d = __builtin_amdgcn_mfma_f32_16x16x32_bf16(a0h, b0, d, 0, 0, 0);
        d = __builtin_amdgcn_mfma_f32_16x16x32_bf16(a0l, b0, d, 0, 0, 0);
        d = __builtin_amdgcn_mfma_f32_16x16x32_bf16(a1h, b1, d, 0, 0, 0);
        d = __builtin_amdgcn_mfma_f32_16x16x32_bf16(a1l, b1, d, 0, 0, 0);
        const float bb = bu[nt * 16 + lr];
        #pragma unroll
        for (int i = 0; i < 4; ++i)
            out[(orow0 + i) * DD + nt * 16 + lr] = d[i] + bb;
    }
}

// ---------------------------------------------------------------------------
extern "C" void kernel_launch(void* const* d_in, const int* in_sizes, int n_in,
                              void* d_out, int out_size, void* d_ws, size_t ws_size,
                              hipStream_t stream) {
    const float* input = (const float*)d_in[0];
    const float* subU  = (const float*)d_in[1];
    const int*   idx   = (const int*)  d_in[2];
    const float* Wd    = (const float*)d_in[3];
    const float* bd    = (const float*)d_in[4];
    const float* Wu    = (const float*)d_in[5];
    const float* bu    = (const float*)d_in[6];
    const float* Wa    = (const float*)d_in[7];
    const float* ba    = (const float*)d_in[8];
    const float* gamma = (const float*)d_in[9];
    const float* beta  = (const float*)d_in[10];
    float* out = (float*)d_out;

    unsigned short* h16  = (unsigned short*)d_ws;          // [BN,64] bf16
    unsigned short* y116 = h16 + 8388608;                  // [BN,64] bf16
    unsigned short* WdB  = y116 + 8388608;                 // 64*384 bf16
    unsigned short* WuB  = WdB + 24576;                    // 384*64 bf16
    unsigned short* WaB  = WuB + 24576;                    // 64*64  bf16

    const float* U1   = subU + 8388608; // sub_U[1] (branch 0 is dead code)
    const int*   idx0 = idx;
    const int*   idx1 = idx + BNROW;

    kP<<<52,   256, 0, stream>>>(Wd, Wu, Wa, WdB, WuB, WaB);
    kA<<<2048, 256, 0, stream>>>(input, WdB, bd, h16);
    kB<<<2048, 256, 0, stream>>>(h16, U1, idx0, WaB, ba, gamma, beta, y116);
    kC<<<2048, 256, 0, stream>>>(h16, y116, idx1, WuB, bu, out);
}